// Round 2
// 1392.395 us; speedup vs baseline: 1.9063x; 1.9063x over previous
//
#include <hip/hip_runtime.h>
#include <math.h>

#define B_     64
#define NPG_   4096
#define M_     8
#define DN_    512
#define DQ_    256
#define N_     (B_*NPG_)
#define KSEL_  1229          // ceil(0.3 * 4096)

typedef _Float16 f16x4  __attribute__((ext_vector_type(4)));
typedef _Float16 f16x8  __attribute__((ext_vector_type(8)));
typedef float    f32x16 __attribute__((ext_vector_type(16)));

// ---------------------------------------------------------------------------
// Kernel 0: split Wn[k][c] (fp32) into transposed fp16 hi/lo halves
// WnT_hi/lo[c][k], k contiguous -> GEMM B-staging reads 64B runs per lane.
// One-time, tiny (512 KB), parked in d_out (k_mask overwrites it later).
// ---------------------------------------------------------------------------
__global__ __launch_bounds__(256) void k_prep(const float* __restrict__ Wn,
                                              _Float16* __restrict__ th,
                                              _Float16* __restrict__ tl)
{
    const int k = blockIdx.x;      // 0..511
    const int c = threadIdx.x;     // 0..255
    const float w = Wn[k * DQ_ + c];
    const _Float16 h = (_Float16)w;
    th[c * DN_ + k] = h;
    tl[c * DN_ + k] = (_Float16)(w - (float)h);
}

// ---------------------------------------------------------------------------
// Kernel 1: scores[n][m] = sum_c gelu(x[n]·Wn[:,c] + bn[c]) * u[m][b(n)][c]
// MFMA fp16x2-split GEMM: acc += xhi*whi + xhi*wlo + xlo*whi (fp32 acc).
// Block: 128 rows x 256 cols (full DQ), 4 waves (each 64x128: 2x4 tiles of
// 32x32x16), BK=32, reg-prefetch single-buffer LDS, pad-to-40-halves rows
// (80B stride -> <=2-way bank conflicts, free per m136). Epilogue: exact-erf
// gelu + u-dot + shfl_xor column reduce + cross-wave LDS combine.
// ---------------------------------------------------------------------------
__global__ __launch_bounds__(256, 2) void k_score(
    const float* __restrict__ x, const float* __restrict__ u,
    const float* __restrict__ bn,
    const _Float16* __restrict__ wth, const _Float16* __restrict__ wtl,
    float* __restrict__ scores)
{
    __shared__ __align__(16) _Float16 Ahi[128][40], Alo[128][40];   // 10240 B each
    __shared__ __align__(16) _Float16 Bhi[256][40], Blo[256][40];   // 20480 B each
    __shared__ float usS[M_][DQ_];                                  // 8192 B
    __shared__ float bnsS[DQ_];                                     // 1024 B
    __shared__ float part2[2][128][M_];                             // 8192 B
    // total ~78.8 KB -> 2 blocks/CU

    const int tid = threadIdx.x;
    const int ln  = tid & 63;
    const int w   = tid >> 6;
    const int wr  = w >> 1;            // 0..1 : 64-row group
    const int wc  = w & 1;             // 0..1 : 128-col group
    const int lr  = ln & 31;
    const int lh  = ln >> 5;
    const int row0 = blockIdx.x * 128;
    const int b    = row0 >> 12;       // graph id (128 rows never straddle)

    // stage instruction vectors + bias (consumed in epilogue; loop barriers cover)
    #pragma unroll
    for (int p = 0; p < 8; ++p) {
        const int idx = p * 256 + tid;
        usS[idx >> 8][idx & 255] = u[((idx >> 8) * B_ + b) * DQ_ + (idx & 255)];
    }
    bnsS[tid] = bn[tid];

    // ---- staging addresses ----
    const int arow = tid >> 1;                 // 0..127
    const int aks  = (tid & 1) * 16;           // 0 or 16 (halves of BK=32)
    const float*  xp  = x + (long)(row0 + arow) * DN_ + aks;
    const float4* bhp = (const float4*)(wth + (long)tid * DN_);   // row c = tid
    const float4* blp = (const float4*)(wtl + (long)tid * DN_);

    float4 xa[4], bh[4], bl[4];
    #pragma unroll
    for (int i = 0; i < 4; ++i) {              // prefetch tile 0
        xa[i] = ((const float4*)xp)[i];
        bh[i] = bhp[i];
        bl[i] = blp[i];
    }

    f32x16 acc[2][4];
    #pragma unroll
    for (int mt = 0; mt < 2; ++mt)
        #pragma unroll
        for (int nt = 0; nt < 4; ++nt)
            #pragma unroll
            for (int r = 0; r < 16; ++r) acc[mt][nt][r] = 0.0f;

    for (int kt = 0; kt < DN_ / 32; ++kt) {
        __syncthreads();                       // previous tile fully consumed

        // write A (convert fp32 -> hi/lo fp16)
        #pragma unroll
        for (int i = 0; i < 4; ++i) {
            const float4 v = xa[i];
            f16x4 h, lo2;
            h[0] = (_Float16)v.x; lo2[0] = (_Float16)(v.x - (float)h[0]);
            h[1] = (_Float16)v.y; lo2[1] = (_Float16)(v.y - (float)h[1]);
            h[2] = (_Float16)v.z; lo2[2] = (_Float16)(v.z - (float)h[2]);
            h[3] = (_Float16)v.w; lo2[3] = (_Float16)(v.w - (float)h[3]);
            *(f16x4*)&Ahi[arow][aks + 4 * i] = h;
            *(f16x4*)&Alo[arow][aks + 4 * i] = lo2;
        }
        // write B (already fp16 bits, straight copy)
        #pragma unroll
        for (int i = 0; i < 4; ++i) {
            *(float4*)&Bhi[tid][i * 8] = bh[i];
            *(float4*)&Blo[tid][i * 8] = bl[i];
        }
        __syncthreads();

        if (kt + 1 < DN_ / 32) {               // prefetch next tile into regs
            const float* xn = xp + (kt + 1) * 32;
            #pragma unroll
            for (int i = 0; i < 4; ++i) {
                xa[i] = ((const float4*)xn)[i];
                bh[i] = bhp[(kt + 1) * 4 + i];
                bl[i] = blp[(kt + 1) * 4 + i];
            }
        }

        // MFMA: 2 K-substeps x 2x4 tiles x 3 split products = 48 MFMA/wave
        #pragma unroll
        for (int s = 0; s < 2; ++s) {
            const int o = s * 16 + lh * 8;
            f16x8 afh[2], afl[2], bfh[4], bfl[4];
            #pragma unroll
            for (int mt = 0; mt < 2; ++mt) {
                const int r = wr * 64 + mt * 32 + lr;
                afh[mt] = *(const f16x8*)&Ahi[r][o];
                afl[mt] = *(const f16x8*)&Alo[r][o];
            }
            #pragma unroll
            for (int nt = 0; nt < 4; ++nt) {
                const int c = wc * 128 + nt * 32 + lr;
                bfh[nt] = *(const f16x8*)&Bhi[c][o];
                bfl[nt] = *(const f16x8*)&Blo[c][o];
            }
            #pragma unroll
            for (int mt = 0; mt < 2; ++mt)
                #pragma unroll
                for (int nt = 0; nt < 4; ++nt) {
                    acc[mt][nt] = __builtin_amdgcn_mfma_f32_32x32x16_f16(
                        afh[mt], bfh[nt], acc[mt][nt], 0, 0, 0);
                    acc[mt][nt] = __builtin_amdgcn_mfma_f32_32x32x16_f16(
                        afh[mt], bfl[nt], acc[mt][nt], 0, 0, 0);
                    acc[mt][nt] = __builtin_amdgcn_mfma_f32_32x32x16_f16(
                        afl[mt], bfh[nt], acc[mt][nt], 0, 0, 0);
                }
        }
    }

    // ---- epilogue: bias + exact gelu, in place ----
    #pragma unroll
    for (int mt = 0; mt < 2; ++mt)
        #pragma unroll
        for (int nt = 0; nt < 4; ++nt) {
            const float bnc = bnsS[wc * 128 + nt * 32 + lr];
            #pragma unroll
            for (int r = 0; r < 16; ++r) {
                const float z = acc[mt][nt][r] + bnc;
                acc[mt][nt][r] = 0.5f * z * (1.0f + erff(z * 0.7071067811865476f));
            }
        }

    // dot with 8 instruction vectors; reduce over the 32 cols held across lanes
    #pragma unroll 1
    for (int m = 0; m < 8; ++m) {
        const float u0 = usS[m][wc * 128 +   0 + lr];
        const float u1 = usS[m][wc * 128 +  32 + lr];
        const float u2 = usS[m][wc * 128 +  64 + lr];
        const float u3 = usS[m][wc * 128 +  96 + lr];
        float p[2][16];
        #pragma unroll
        for (int mt = 0; mt < 2; ++mt)
            #pragma unroll
            for (int r = 0; r < 16; ++r)
                p[mt][r] = acc[mt][0][r] * u0 + acc[mt][1][r] * u1
                         + acc[mt][2][r] * u2 + acc[mt][3][r] * u3;
        #pragma unroll
        for (int mask = 1; mask < 32; mask <<= 1)
            #pragma unroll
            for (int mt = 0; mt < 2; ++mt)
                #pragma unroll
                for (int r = 0; r < 16; ++r)
                    p[mt][r] += __shfl_xor(p[mt][r], mask, 64);
        if (lr == m) {                          // lanes m and 32+m write their halves
            #pragma unroll
            for (int mt = 0; mt < 2; ++mt)
                #pragma unroll
                for (int r = 0; r < 16; ++r) {
                    const int row = wr * 64 + mt * 32 + (r & 3) + 8 * (r >> 2) + 4 * lh;
                    part2[wc][row][m] = p[mt][r];
                }
        }
    }
    __syncthreads();

    // combine the two col-halves, coalesced store
    #pragma unroll
    for (int i = 0; i < 4; ++i) {
        const int idx = i * 256 + tid;
        const int row = idx >> 3, m = idx & 7;
        scores[(long)(row0 + row) * M_ + m] = part2[0][row][m] + part2[1][row][m];
    }
}

// ---------------------------------------------------------------------------
// Kernel 2: per-graph softmax-normalize -> gate -> exact top-K threshold
// (4-pass radix select on float bit patterns; gates are >= 0) -> binary mask.
// One block (256 threads) per graph.  (Unchanged from verified baseline.)
// ---------------------------------------------------------------------------
__global__ __launch_bounds__(256) void k_mask(
    const float* __restrict__ scores, float* __restrict__ out)
{
    __shared__ float red[256];
    __shared__ float gateLDS[NPG_];
    __shared__ float gmaxS[M_];
    __shared__ float ginvS[M_];
    __shared__ unsigned hist[256];
    __shared__ unsigned sPrefix;
    __shared__ int sWant;

    const int b   = blockIdx.x;
    const int tid = threadIdx.x;
    const float* sb = scores + (long)b * NPG_ * M_;

    // pass A: per-m max over the graph's 4096 nodes
    float lmax[8];
    #pragma unroll
    for (int m = 0; m < 8; ++m) lmax[m] = -INFINITY;
    for (int it = 0; it < 16; ++it) {
        const int n = it * 256 + tid;
        const float4 s0 = *(const float4*)(sb + (long)n * 8);
        const float4 s1 = *(const float4*)(sb + (long)n * 8 + 4);
        lmax[0] = fmaxf(lmax[0], s0.x); lmax[1] = fmaxf(lmax[1], s0.y);
        lmax[2] = fmaxf(lmax[2], s0.z); lmax[3] = fmaxf(lmax[3], s0.w);
        lmax[4] = fmaxf(lmax[4], s1.x); lmax[5] = fmaxf(lmax[5], s1.y);
        lmax[6] = fmaxf(lmax[6], s1.z); lmax[7] = fmaxf(lmax[7], s1.w);
    }
    for (int m = 0; m < 8; ++m) {
        red[tid] = lmax[m]; __syncthreads();
        for (int s = 128; s > 0; s >>= 1) {
            if (tid < s) red[tid] = fmaxf(red[tid], red[tid + s]);
            __syncthreads();
        }
        if (tid == 0) gmaxS[m] = red[0];
        __syncthreads();
    }

    // pass B: per-m sum of exp(s - max)
    float lsum[8];
    #pragma unroll
    for (int m = 0; m < 8; ++m) lsum[m] = 0.0f;
    for (int it = 0; it < 16; ++it) {
        const int n = it * 256 + tid;
        const float4 s0 = *(const float4*)(sb + (long)n * 8);
        const float4 s1 = *(const float4*)(sb + (long)n * 8 + 4);
        lsum[0] += expf(s0.x - gmaxS[0]); lsum[1] += expf(s0.y - gmaxS[1]);
        lsum[2] += expf(s0.z - gmaxS[2]); lsum[3] += expf(s0.w - gmaxS[3]);
        lsum[4] += expf(s1.x - gmaxS[4]); lsum[5] += expf(s1.y - gmaxS[5]);
        lsum[6] += expf(s1.z - gmaxS[6]); lsum[7] += expf(s1.w - gmaxS[7]);
    }
    for (int m = 0; m < 8; ++m) {
        red[tid] = lsum[m]; __syncthreads();
        for (int s = 128; s > 0; s >>= 1) {
            if (tid < s) red[tid] += red[tid + s];
            __syncthreads();
        }
        if (tid == 0) ginvS[m] = 1.0f / red[0];
        __syncthreads();
    }

    // pass C: gate[n] = sum_m attn
    for (int it = 0; it < 16; ++it) {
        const int n = it * 256 + tid;
        const float4 s0 = *(const float4*)(sb + (long)n * 8);
        const float4 s1 = *(const float4*)(sb + (long)n * 8 + 4);
        float g = 0.0f;
        g += expf(s0.x - gmaxS[0]) * ginvS[0];
        g += expf(s0.y - gmaxS[1]) * ginvS[1];
        g += expf(s0.z - gmaxS[2]) * ginvS[2];
        g += expf(s0.w - gmaxS[3]) * ginvS[3];
        g += expf(s1.x - gmaxS[4]) * ginvS[4];
        g += expf(s1.y - gmaxS[5]) * ginvS[5];
        g += expf(s1.z - gmaxS[6]) * ginvS[6];
        g += expf(s1.w - gmaxS[7]) * ginvS[7];
        gateLDS[n] = g;
    }
    __syncthreads();

    // pass D: exact K-th largest via 4x8-bit radix select on float bits
    if (tid == 0) { sPrefix = 0u; sWant = KSEL_; }
    __syncthreads();
    const unsigned himask[4] = {0u, 0xFF000000u, 0xFFFF0000u, 0xFFFFFF00u};
    for (int r = 0; r < 4; ++r) {
        hist[tid] = 0u;
        __syncthreads();
        const unsigned pfx = sPrefix;
        const unsigned hm  = himask[r];
        const int shift = 24 - 8 * r;
        for (int it = 0; it < 16; ++it) {
            const unsigned uv = __float_as_uint(gateLDS[it * 256 + tid]);
            if ((uv & hm) == pfx)
                atomicAdd(&hist[(uv >> shift) & 255u], 1u);
        }
        __syncthreads();
        if (tid == 0) {
            int want = sWant;
            unsigned acc = 0u;
            for (int bb = 255; bb >= 0; --bb) {
                const unsigned h = hist[bb];
                if (acc + h >= (unsigned)want) {
                    sWant   = want - (int)acc;
                    sPrefix = pfx | ((unsigned)bb << shift);
                    break;
                }
                acc += h;
            }
        }
        __syncthreads();
    }
    const float kth = __uint_as_float(sPrefix);

    // pass E: mask = gate >= kth
    for (int it = 0; it < 16; ++it) {
        const int n = it * 256 + tid;
        out[(long)b * NPG_ + n] = (gateLDS[n] >= kth) ? 1.0f : 0.0f;
    }
}

extern "C" void kernel_launch(void* const* d_in, const int* in_sizes, int n_in,
                              void* d_out, int out_size, void* d_ws, size_t ws_size,
                              hipStream_t stream) {
    const float* x  = (const float*)d_in[0];
    const float* u  = (const float*)d_in[1];
    const float* Wn = (const float*)d_in[2];
    const float* bn = (const float*)d_in[3];
    // d_in[4] = batch (equal segments, implied by layout), d_in[5] = edge_index (unused)

    float* scores = (float*)d_ws;              // N_ * M_ floats = 8 MB

    // WnT hi/lo (512 KB) parked in d_out (1 MB); k_mask fully overwrites out later.
    _Float16* wth = (_Float16*)d_out;
    _Float16* wtl = wth + DQ_ * DN_;
    float* out    = (float*)d_out;

    k_prep <<<DN_, 256, 0, stream>>>(Wn, wth, wtl);
    k_score<<<N_ / 128, 256, 0, stream>>>(x, u, bn, wth, wtl, scores);
    k_mask <<<B_, 256, 0, stream>>>(scores, out);
}